// Round 6
// baseline (2410.736 us; speedup 1.0000x reference)
//
#include <hip/hip_runtime.h>
#include <math.h>

// ---------------------------------------------------------------------------
// SNN forward. Round-6: rec stripes remapped chain-local per XCD
// (bid = s*32+b so bid%8 = b%8), per-stripe monotonic release-store flags
// (no RMW counter), parity-reused mask/fc slots, wave0-only sync phase,
// 4 barriers/step. Round-5 failed because stripes of a chain sat on 6
// different XCDs and fresh per-step slots streamed 38MB through the LLC.
// ---------------------------------------------------------------------------

#define BATCH 32
#define TSTEPS 150
#define C1N 1470            // 30*7*7 (trimmed: pooled conv2 only needs 7x7)
#define ZSEQN 70
#define HID1 512
#define HID2 1024
#define K1CAT 582           // rows: [rec(512) | conv(70)]
#define K2CAT 1094          // rows: [rec(1024) | conv(70)]

#define N_Z    (BATCH*TSTEPS*ZSEQN)   // 336,000
#define N_W1T  (K1CAT*HID1)           // 297,984
#define N_W2T  (K2CAT*HID2)           // 1,120,256
#define N_ST0  (BATCH*2*C1N)          // 94,080
#define N_ST2  (BATCH*2*ZSEQN)        // 4,480

// exchange: per role-1 chain: flags[32] + 2 slots[128] = 320 u32
//           per role-0 chain: flags[32] + 2 slots[64]  = 160 u32
#define CH1_EX 320
#define CH0_EX 160
#define OFF_EX0 (32*CH1_EX)
#define N_EXCH (32*CH1_EX + 32*CH0_EX)    // 15,360 u32 = 61 KB

// -------------------------------------------------------------------- K0 ---
__global__ void prep_weights(const float* __restrict__ l1_in_w,
                             const float* __restrict__ l1_rec_w,
                             const float* __restrict__ cl_in_w,
                             const float* __restrict__ cl_rec_w,
                             float* __restrict__ w1t,
                             float* __restrict__ w2t) {
    int idx = blockIdx.x * blockDim.x + threadIdx.x;
    int stride = gridDim.x * blockDim.x;
    for (int e = idx; e < N_W1T; e += stride) {
        int j = e / HID1, o = e - j * HID1;
        w1t[e] = (j < HID1) ? l1_rec_w[o * HID1 + j] : l1_in_w[o * 70 + (j - HID1)];
    }
    for (int e = idx; e < N_W2T; e += stride) {
        int j = e / HID2, o = e - j * HID2;
        w2t[e] = (j < HID2) ? cl_rec_w[o * HID2 + j] : cl_in_w[o * 70 + (j - HID2)];
    }
}

__global__ void init_exch(unsigned int* __restrict__ exch) {
    int idx = blockIdx.x * blockDim.x + threadIdx.x;
    int stride = gridDim.x * blockDim.x;
    for (int e = idx; e < N_EXCH; e += stride) exch[e] = 0u;
}

// -------------------------------------------------------------------- K1 ---
__global__ __launch_bounds__(640) void conv1_pool(const float* __restrict__ x,
                                                  const float* __restrict__ w1,
                                                  const float* __restrict__ b1,
                                                  float* __restrict__ c1buf,
                                                  int t0, int CH) {
    __shared__ float img[2 * 34 * 34];
    __shared__ float w1s[30 * 2 * 49];
    __shared__ float crow[630 * 21];
    int bid = blockIdx.x;
    int b = bid / CH, tc = bid - b * CH;
    int t = t0 + tc;
    int tid = threadIdx.x;
    const float* xin = x + (size_t)(b * TSTEPS + t) * 2312;
    for (int e = tid; e < 2312; e += 640) img[e] = xin[e];
    for (int e = tid; e < 2940; e += 640) w1s[e] = w1[e];
    __syncthreads();
    if (tid < 630) {
        int oc = tid / 21, cy = tid - oc * 21;
        float acc[21];
        #pragma unroll
        for (int j = 0; j < 21; ++j) acc[j] = 0.f;
        #pragma unroll
        for (int ic = 0; ic < 2; ++ic) {
            const float* irow0 = &img[ic * 1156];
            const float* wrow = &w1s[(oc * 2 + ic) * 49];
            #pragma unroll
            for (int ky = 0; ky < 7; ++ky) {
                const float* ir = &irow0[(cy + ky) * 34];
                float r[27];
                #pragma unroll
                for (int j = 0; j < 27; ++j) r[j] = ir[j];
                #pragma unroll
                for (int kx = 0; kx < 7; ++kx) {
                    float w = wrow[ky * 7 + kx];
                    #pragma unroll
                    for (int cx = 0; cx < 21; ++cx)
                        acc[cx] = fmaf(r[cx + kx], w, acc[cx]);
                }
            }
        }
        #pragma unroll
        for (int cx = 0; cx < 21; ++cx) crow[tid * 21 + cx] = acc[cx];
    }
    __syncthreads();
    float* c1 = c1buf + (size_t)bid * C1N;
    for (int p = tid; p < C1N; p += 640) {
        int oc = p / 49; int r = p - oc * 49; int py = r / 7, px = r - py * 7;
        float m = -1e30f;
        #pragma unroll
        for (int dy = 0; dy < 3; ++dy) {
            int rowid = oc * 21 + 3 * py + dy;
            #pragma unroll
            for (int dx = 0; dx < 3; ++dx)
                m = fmaxf(m, crow[rowid * 21 + 3 * px + dx]);
        }
        c1[p] = m + b1[oc];
    }
}

// -------------------------------------------------------------------- K2 ---
__global__ __launch_bounds__(320) void conv2_chain(const float* __restrict__ w2,
                                                   const float* __restrict__ b2,
                                                   const float* __restrict__ c1buf,
                                                   float* __restrict__ zbuf,
                                                   const float* __restrict__ st0_in,
                                                   float* __restrict__ st0_out,
                                                   const float* __restrict__ st2_in,
                                                   float* __restrict__ st2_out,
                                                   int t0, int CH) {
    int bid = blockIdx.x;
    int b = bid >> 3, w = bid & 7;
    int ocStart = w * 9;
    int nOc = (w == 7) ? 7 : 9;
    int tid = threadIdx.x;
    __shared__ float v0[C1N], i0[C1N], z0[C1N];
    __shared__ float w2s[9 * 750];
    __shared__ float part[9 * 30 * 9];
    __shared__ float red[81];
    for (int e = tid; e < nOc * 750; e += 320) w2s[e] = w2[ocStart * 750 + e];
    float v2 = 0.f, i2 = 0.f;
    if (t0 == 0) {
        for (int e = tid; e < C1N; e += 320) { v0[e] = 0.f; i0[e] = 0.f; }
    } else {
        const float* s0 = st0_in + (size_t)b * 2 * C1N;
        for (int e = tid; e < C1N; e += 320) { v0[e] = s0[e]; i0[e] = s0[C1N + e]; }
        if (tid < nOc) {
            v2 = st2_in[b * ZSEQN + ocStart + tid];
            i2 = st2_in[BATCH * ZSEQN + b * ZSEQN + ocStart + tid];
        }
    }
    float bias2 = (tid < nOc) ? b2[ocStart + tid] : 0.f;
    __syncthreads();
    const float* c1b = c1buf + (size_t)b * CH * C1N;
    float* zs = zbuf + (size_t)b * TSTEPS * ZSEQN;
    int nConv = nOc * 30;
    for (int tc = 0; tc < CH; ++tc) {
        const float* c1t = c1b + (size_t)tc * C1N;
        for (int e = tid; e < C1N; e += 320) {
            float v = v0[e], i = i0[e];
            float vd = v + 0.1f * (i - v);
            float id = i - 0.2f * i;
            bool sp = (vd > 1.0f);
            v0[e] = sp ? 0.f : vd;
            i0[e] = id + c1t[e];
            z0[e] = sp ? 1.f : 0.f;
        }
        __syncthreads();
        if (tid < nConv) {
            int ol = tid / 30, ic = tid - ol * 30;
            float zw[49];
            #pragma unroll
            for (int j = 0; j < 49; ++j) zw[j] = z0[ic * 49 + j];
            float a[9];
            #pragma unroll
            for (int p = 0; p < 9; ++p) a[p] = 0.f;
            const float* wb = &w2s[ol * 750 + ic * 25];
            #pragma unroll
            for (int ky = 0; ky < 5; ++ky)
                #pragma unroll
                for (int kx = 0; kx < 5; ++kx) {
                    float wv = wb[ky * 5 + kx];
                    #pragma unroll
                    for (int cy = 0; cy < 3; ++cy)
                        #pragma unroll
                        for (int cx = 0; cx < 3; ++cx)
                            a[cy * 3 + cx] = fmaf(zw[(cy + ky) * 7 + cx + kx], wv, a[cy * 3 + cx]);
                }
            #pragma unroll
            for (int p = 0; p < 9; ++p) part[tid * 9 + p] = a[p];
        }
        __syncthreads();
        if (tid < nOc * 9) {
            int ol = tid / 9, pos = tid - ol * 9;
            float s = 0.f;
            for (int ic = 0; ic < 30; ++ic) s += part[(ol * 30 + ic) * 9 + pos];
            red[tid] = s;
        }
        __syncthreads();
        if (tid < nOc) {
            float m = -1e30f;
            #pragma unroll
            for (int p = 0; p < 9; ++p) m = fmaxf(m, red[tid * 9 + p]);
            float inp = m + bias2;
            float vd = v2 + 0.1f * (i2 - v2);
            float id = i2 - 0.2f * i2;
            bool sp = (vd > 1.0f);
            v2 = sp ? 0.f : vd;
            i2 = id + inp;
            zs[(size_t)(t0 + tc) * ZSEQN + ocStart + tid] = sp ? 1.f : 0.f;
        }
        __syncthreads();
    }
    if (w == 0) {
        float* s0 = st0_out + (size_t)b * 2 * C1N;
        for (int e = tid; e < C1N; e += 320) { s0[e] = v0[e]; s0[C1N + e] = i0[e]; }
    }
    if (tid < nOc) {
        st2_out[b * ZSEQN + ocStart + tid] = v2;
        st2_out[BATCH * ZSEQN + b * ZSEQN + ocStart + tid] = i2;
    }
}

// -------------------------------------------------------------------- K3 ---
__device__ __forceinline__ float4 f4add(float4 a, const float4 b) {
    a.x += b.x; a.y += b.y; a.z += b.z; a.w += b.w; return a;
}
__device__ __forceinline__ void ast(unsigned int* p, unsigned int v) {
    __hip_atomic_store(p, v, __ATOMIC_RELAXED, __HIP_MEMORY_SCOPE_AGENT);
}
__device__ __forceinline__ unsigned int ald(unsigned int* p) {
    return __hip_atomic_load(p, __ATOMIC_RELAXED, __HIP_MEMORY_SCOPE_AGENT);
}

// One 128-col stripe of one chain per WG (256 threads, 4 waves).
// chex: flags[32] | slot0 | slot1.  slot: masks[4*CS] | fc[CS*R].
template <int ROLE>
__device__ __forceinline__ void rec_stripe_body(
        int b, int sid,
        const float* __restrict__ fcw,
        const float* __restrict__ zbuf,
        const float* __restrict__ catT,
        unsigned int* __restrict__ chex,
        float* __restrict__ out,
        float* fcwl, float* part, unsigned short* list,
        unsigned int* maskw, unsigned int* wprefix, float* wpart,
        float* fcbuf, float* mvals) {
    constexpr int N     = ROLE ? HID2 : HID1;
    constexpr int K     = ROLE ? K2CAT : K1CAT;
    constexpr int R     = ROLE ? 10 : 4;
    constexpr int CS    = ROLE ? 8 : 4;
    constexpr int NW    = N / 32;          // rec mask words (= 4*CS)
    constexpr int NWT   = NW + 3;          // + 3 conv words
    constexpr int SLOTSZ= ROLE ? 128 : 64;
    constexpr int COLS  = 128, PSTR = 132;
    constexpr int N4    = N / 4;

    unsigned int* flags = chex;
    unsigned int* slots = chex + 32;

    const int t = threadIdx.x;
    const int lane = t & 63, wv = t >> 6;
    const int aid = t >> 5, qid = t & 31;   // 8 A-slices x 32 quads
    const int base = sid * 32 + qid;

    for (int e = t; e < R * COLS; e += 256)
        fcwl[e] = fcw[(e >> 7) * N + sid * COLS + (e & 127)];

    const float* zsb = zbuf + (size_t)b * TSTEPS * ZSEQN;
    const float4* __restrict__ catT4 = (const float4*)catT;

    float v = 0.f, iacc = 0.f;
    float vli = 0.f, ili = 0.f, rmax = -1e30f;

    // ---- initial list: rec bits 0, conv bits from zsb[0] ----
    if (t < NW) maskw[t] = 0u;
    {
        float zc = (t < 70) ? zsb[t] : 0.f;
        unsigned long long mc = __ballot(zc != 0.f);
        if (lane == 0) {
            if (wv == 0) { maskw[NW] = (unsigned)mc; maskw[NW + 1] = (unsigned)(mc >> 32); }
            else if (wv == 1) { maskw[NW + 2] = (unsigned)(mc & 0x3full); }
        }
    }
    __syncthreads();
    if (wv == 0) {
        unsigned val = (lane < NWT) ? __popc(maskw[lane]) : 0u;
        #pragma unroll
        for (int d = 1; d < 64; d <<= 1) {
            unsigned u = __shfl_up(val, d);
            if (lane >= d) val += u;
        }
        if (lane < NWT) wprefix[lane + 1] = val;
        if (lane == 0) wprefix[0] = 0u;
    }
    __syncthreads();
    int A = wprefix[NWT];
    for (int jj = t; jj < K; jj += 256) {
        unsigned m = maskw[jj >> 5];
        if ((m >> (jj & 31)) & 1u)
            list[wprefix[jj >> 5] + __popc(m & ((1u << (jj & 31)) - 1u))] = (unsigned short)jj;
    }
    __syncthreads();

    for (int tt = 0; tt < TSTEPS; ++tt) {
        float znext = (t < 70 && tt + 1 < TSTEPS) ? zsb[(size_t)(tt + 1) * ZSEQN + t] : 0.f;
        // ---- stripe gather over active rows ----
        float4 s0 = {0.f, 0.f, 0.f, 0.f}, s1 = s0, s2 = s0, s3 = s0;
        int idx = aid;
        for (; idx + 24 < A; idx += 32) {
            s0 = f4add(s0, catT4[(size_t)list[idx]      * N4 + base]);
            s1 = f4add(s1, catT4[(size_t)list[idx + 8]  * N4 + base]);
            s2 = f4add(s2, catT4[(size_t)list[idx + 16] * N4 + base]);
            s3 = f4add(s3, catT4[(size_t)list[idx + 24] * N4 + base]);
        }
        for (; idx < A; idx += 8) s0 = f4add(s0, catT4[(size_t)list[idx] * N4 + base]);
        s0 = f4add(f4add(s0, s1), f4add(s2, s3));
        *(float4*)(part + aid * PSTR + 4 * qid) = s0;
        __syncthreads();                                   // B1: part ready
        unsigned int* slot = slots + ((tt + 1) & 1) * SLOTSZ;
        float znew = 0.f;
        if (t < COLS) {
            float cur = 0.f;
            #pragma unroll
            for (int a = 0; a < 8; ++a) cur += part[a * PSTR + t];
            float vd = v + 0.1f * (iacc - v);
            float id = iacc - 0.2f * iacc;
            bool sp = (vd > 0.4f);
            znew = sp ? 1.f : 0.f;
            v = sp ? 0.f : vd;
            iacc = id + cur;
        }
        // spike masks for this stripe -> slot (waves 0,1)
        unsigned long long mz = __ballot(znew != 0.f);
        if (lane == 0 && wv < 2) {
            ast(slot + sid * 4 + wv * 2,     (unsigned)mz);
            ast(slot + sid * 4 + wv * 2 + 1, (unsigned)(mz >> 32));
        }
        // conv mask for NEXT step -> LDS (waves 0,1)
        {
            unsigned long long mc = __ballot(znext != 0.f);
            if (lane == 0) {
                if (wv == 0) { maskw[NW] = (unsigned)mc; maskw[NW + 1] = (unsigned)(mc >> 32); }
                else if (wv == 1) { maskw[NW + 2] = (unsigned)(mc & 0x3full); }
            }
        }
        // fc partials: per-wave shuffle reduce
        #pragma unroll
        for (int k = 0; k < R; ++k) {
            float c = (t < COLS && znew != 0.f) ? fcwl[k * COLS + t] : 0.f;
            #pragma unroll
            for (int off = 32; off; off >>= 1) c += __shfl_xor(c, off);
            if (lane == 0) wpart[k * 4 + wv] = c;
        }
        __syncthreads();                     // B2: all stores drained (vmcnt 0)
        if (wv == 0) {
            if (t < R) {
                float s = wpart[t * 4] + wpart[t * 4 + 1] + wpart[t * 4 + 2] + wpart[t * 4 + 3];
                ast(slot + 4 * CS + sid * R + t, __float_as_uint(s));
            }
            if (lane == 0)
                __hip_atomic_store(flags + sid, (unsigned)(tt + 1),
                                   __ATOMIC_RELEASE, __HIP_MEMORY_SCOPE_AGENT);
            if (t < CS) {
                while (__hip_atomic_load(flags + t, __ATOMIC_ACQUIRE,
                                         __HIP_MEMORY_SCOPE_AGENT) < (unsigned)(tt + 1))
                    __builtin_amdgcn_s_sleep(1);
            }
            if (lane < NW) maskw[lane] = ald(slot + lane);
            if (sid == 0) {
                for (int e = lane; e < CS * R; e += 64)
                    fcbuf[e] = __uint_as_float(ald(slot + 4 * CS + e));
            }
            unsigned val = (lane < NWT) ? __popc(maskw[lane]) : 0u;
            #pragma unroll
            for (int d = 1; d < 64; d <<= 1) {
                unsigned u = __shfl_up(val, d);
                if (lane >= d) val += u;
            }
            if (lane < NWT) wprefix[lane + 1] = val;
            if (lane == 0) wprefix[0] = 0u;
            // leader LI update (wave 0, after fcbuf loads)
            if (sid == 0 && lane < R) {
                float inp = 0.f;
                #pragma unroll
                for (int u = 0; u < CS; ++u) inp += fcbuf[u * R + lane];
                float vn = vli + 0.1f * (ili - vli);
                ili = ili - 0.2f * ili + inp;
                vli = vn;
                rmax = fmaxf(rmax, vn);
            }
        }
        __syncthreads();                                   // B3: maskw/wprefix
        A = wprefix[NWT];
        for (int jj = t; jj < K; jj += 256) {
            unsigned m = maskw[jj >> 5];
            if ((m >> (jj & 31)) & 1u)
                list[wprefix[jj >> 5] + __popc(m & ((1u << (jj & 31)) - 1u))] = (unsigned short)jj;
        }
        __syncthreads();                                   // B4: list ready
    }

    if (sid == 0) {
        if (ROLE == 1) {
            if (t < 10) mvals[t] = rmax;
            __syncthreads();
            if (t < 10) {
                float M = -1e30f;
                #pragma unroll
                for (int k = 0; k < 10; ++k) M = fmaxf(M, mvals[k]);
                float s = 0.f;
                #pragma unroll
                for (int k = 0; k < 10; ++k) s += expf(mvals[k] - M);
                out[BATCH * 4 + b * 10 + t] = mvals[t] - M - logf(s);
            }
        } else {
            if (t < 4) out[b * 4 + t] = rmax;
        }
    }
}

__global__ __launch_bounds__(256) void rec_stripe(const float* __restrict__ fc_out_w,
                                                  const float* __restrict__ cl_fc_w,
                                                  const float* __restrict__ zbuf,
                                                  const float* __restrict__ w1t,
                                                  const float* __restrict__ w2t,
                                                  unsigned int* __restrict__ exch,
                                                  float* __restrict__ out) {
    __shared__ float fcwl[1280];
    __shared__ float part[1056];
    __shared__ unsigned short list[K2CAT];
    __shared__ unsigned int maskw[36];
    __shared__ unsigned int wprefix[36];
    __shared__ float wpart[40];
    __shared__ float fcbuf[80];
    __shared__ float mvals[10];

    int bid = blockIdx.x;
    if (bid < 256) {
        int s = bid >> 5, b = bid & 31;     // bid%8 == b%8 -> chain-local XCD
        rec_stripe_body<1>(b, s, cl_fc_w, zbuf, w2t,
                           exch + (size_t)b * CH1_EX,
                           out, fcwl, part, list, maskw, wprefix, wpart, fcbuf, mvals);
    } else {
        int idx = bid - 256;
        int s = idx >> 5, b = idx & 31;
        rec_stripe_body<0>(b, s, fc_out_w, zbuf, w1t,
                           exch + OFF_EX0 + (size_t)b * CH0_EX,
                           out, fcwl, part, list, maskw, wprefix, wpart, fcbuf, mvals);
    }
}

// ---------------------------------------------------------------------------
extern "C" void kernel_launch(void* const* d_in, const int* in_sizes, int n_in,
                              void* d_out, int out_size, void* d_ws, size_t ws_size,
                              hipStream_t stream) {
    const float* x        = (const float*)d_in[0];
    const float* w1       = (const float*)d_in[1];
    const float* b1       = (const float*)d_in[2];
    const float* w2       = (const float*)d_in[3];
    const float* b2       = (const float*)d_in[4];
    const float* l1_in_w  = (const float*)d_in[5];
    const float* l1_rec_w = (const float*)d_in[6];
    const float* fc_out_w = (const float*)d_in[7];
    const float* cl_in_w  = (const float*)d_in[8];
    const float* cl_rec_w = (const float*)d_in[9];
    const float* cl_fc_w  = (const float*)d_in[10];
    float* out = (float*)d_out;
    float* ws  = (float*)d_ws;

    size_t base = (size_t)N_Z + N_W1T + N_W2T + N_EXCH + 2 * (N_ST0 + N_ST2);
    size_t avail = ws_size / 4;
    static const int divs[] = {150, 75, 50, 30, 25, 15, 10, 6, 5, 3, 2, 1};
    int CH = 1;
    for (int i = 0; i < 12; ++i) {
        size_t need = base + (size_t)BATCH * divs[i] * C1N;
        if (need <= avail) { CH = divs[i]; break; }
    }
    float* zbuf = ws;
    float* w1t  = zbuf + N_Z;
    float* w2t  = w1t + N_W1T;
    unsigned int* exch = (unsigned int*)(w2t + N_W2T);
    float* st0a = w2t + N_W2T + N_EXCH;
    float* st0b = st0a + N_ST0;
    float* st2a = st0b + N_ST0;
    float* st2b = st2a + N_ST2;
    float* c1buf = st2b + N_ST2;

    prep_weights<<<dim3(512), dim3(256), 0, stream>>>(l1_in_w, l1_rec_w,
                                                      cl_in_w, cl_rec_w, w1t, w2t);
    init_exch<<<dim3(16), dim3(256), 0, stream>>>(exch);
    int nChunks = TSTEPS / CH;
    for (int c = 0; c < nChunks; ++c) {
        int t0 = c * CH;
        int par = c & 1;
        const float* s0i = par ? st0b : st0a;
        float*       s0o = par ? st0a : st0b;
        const float* s2i = par ? st2b : st2a;
        float*       s2o = par ? st2a : st2b;
        conv1_pool<<<dim3(BATCH * CH), dim3(640), 0, stream>>>(x, w1, b1, c1buf, t0, CH);
        conv2_chain<<<dim3(256), dim3(320), 0, stream>>>(w2, b2, c1buf, zbuf,
                                                         s0i, s0o, s2i, s2o, t0, CH);
    }
    rec_stripe<<<dim3(384), dim3(256), 0, stream>>>(fc_out_w, cl_fc_w, zbuf,
                                                    w1t, w2t, exch, out);
}

// Round 7
// 1283.874 us; speedup vs baseline: 1.8777x; 1.8777x over previous
//
#include <hip/hip_runtime.h>
#include <math.h>

// ---------------------------------------------------------------------------
// SNN forward. Round-7 rec redesign: 64-col stripes (16/chain role-1,
// 8/chain role-0, 768 stripe WGs = 3/CU), spike masks exchanged as
// RELAXED tagged u64 words ((tt+1)<<32 | mask32) into a per-step archive
// (write-once, no overwrite hazard, no fences, no flags). fc/LI readout
// done by 64 dedicated reader WGs trailing the archive (off critical path).
// Stripe weights XCD-pinned via bid%8 == s%8.
// ---------------------------------------------------------------------------

#define BATCH 32
#define TSTEPS 150
#define C1N 1470            // 30*7*7 (trimmed: pooled conv2 only needs 7x7)
#define ZSEQN 70
#define HID1 512
#define HID2 1024
#define K1CAT 582           // rows: [rec(512) | conv(70)]
#define K2CAT 1094          // rows: [rec(1024) | conv(70)]

#define N_Z    (BATCH*TSTEPS*ZSEQN)   // 336,000
#define N_W1T  (K1CAT*HID1)           // 297,984
#define N_W2T  (K2CAT*HID2)           // 1,120,256
#define N_ST0  (BATCH*2*C1N)          // 94,080
#define N_ST2  (BATCH*2*ZSEQN)        // 4,480

// mask archive (u64): role1 [b][tt][32 words], role0 [b][tt][16 words]
#define A1_U64 (BATCH*TSTEPS*32)      // 153,600
#define A0_U64 (BATCH*TSTEPS*16)      // 76,800
#define N_ARCH_F ((A1_U64+A0_U64)*2)  // float-equivalents = 460,800 (1.84 MB)

// -------------------------------------------------------------------- K0 ---
__global__ void prep_weights(const float* __restrict__ l1_in_w,
                             const float* __restrict__ l1_rec_w,
                             const float* __restrict__ cl_in_w,
                             const float* __restrict__ cl_rec_w,
                             float* __restrict__ w1t,
                             float* __restrict__ w2t) {
    int idx = blockIdx.x * blockDim.x + threadIdx.x;
    int stride = gridDim.x * blockDim.x;
    for (int e = idx; e < N_W1T; e += stride) {
        int j = e / HID1, o = e - j * HID1;
        w1t[e] = (j < HID1) ? l1_rec_w[o * HID1 + j] : l1_in_w[o * 70 + (j - HID1)];
    }
    for (int e = idx; e < N_W2T; e += stride) {
        int j = e / HID2, o = e - j * HID2;
        w2t[e] = (j < HID2) ? cl_rec_w[o * HID2 + j] : cl_in_w[o * 70 + (j - HID2)];
    }
}

__global__ void init_arch(unsigned long long* __restrict__ arch) {
    size_t idx = (size_t)blockIdx.x * blockDim.x + threadIdx.x;
    size_t stride = (size_t)gridDim.x * blockDim.x;
    for (size_t e = idx; e < (A1_U64 + A0_U64); e += stride) arch[e] = 0ull;
}

// -------------------------------------------------------------------- K1 ---
__global__ __launch_bounds__(640) void conv1_pool(const float* __restrict__ x,
                                                  const float* __restrict__ w1,
                                                  const float* __restrict__ b1,
                                                  float* __restrict__ c1buf,
                                                  int t0, int CH) {
    __shared__ float img[2 * 34 * 34];
    __shared__ float w1s[30 * 2 * 49];
    __shared__ float crow[630 * 21];
    int bid = blockIdx.x;
    int b = bid / CH, tc = bid - b * CH;
    int t = t0 + tc;
    int tid = threadIdx.x;
    const float* xin = x + (size_t)(b * TSTEPS + t) * 2312;
    for (int e = tid; e < 2312; e += 640) img[e] = xin[e];
    for (int e = tid; e < 2940; e += 640) w1s[e] = w1[e];
    __syncthreads();
    if (tid < 630) {
        int oc = tid / 21, cy = tid - oc * 21;
        float acc[21];
        #pragma unroll
        for (int j = 0; j < 21; ++j) acc[j] = 0.f;
        #pragma unroll
        for (int ic = 0; ic < 2; ++ic) {
            const float* irow0 = &img[ic * 1156];
            const float* wrow = &w1s[(oc * 2 + ic) * 49];
            #pragma unroll
            for (int ky = 0; ky < 7; ++ky) {
                const float* ir = &irow0[(cy + ky) * 34];
                float r[27];
                #pragma unroll
                for (int j = 0; j < 27; ++j) r[j] = ir[j];
                #pragma unroll
                for (int kx = 0; kx < 7; ++kx) {
                    float w = wrow[ky * 7 + kx];
                    #pragma unroll
                    for (int cx = 0; cx < 21; ++cx)
                        acc[cx] = fmaf(r[cx + kx], w, acc[cx]);
                }
            }
        }
        #pragma unroll
        for (int cx = 0; cx < 21; ++cx) crow[tid * 21 + cx] = acc[cx];
    }
    __syncthreads();
    float* c1 = c1buf + (size_t)bid * C1N;
    for (int p = tid; p < C1N; p += 640) {
        int oc = p / 49; int r = p - oc * 49; int py = r / 7, px = r - py * 7;
        float m = -1e30f;
        #pragma unroll
        for (int dy = 0; dy < 3; ++dy) {
            int rowid = oc * 21 + 3 * py + dy;
            #pragma unroll
            for (int dx = 0; dx < 3; ++dx)
                m = fmaxf(m, crow[rowid * 21 + 3 * px + dx]);
        }
        c1[p] = m + b1[oc];
    }
}

// -------------------------------------------------------------------- K2 ---
__global__ __launch_bounds__(320) void conv2_chain(const float* __restrict__ w2,
                                                   const float* __restrict__ b2,
                                                   const float* __restrict__ c1buf,
                                                   float* __restrict__ zbuf,
                                                   const float* __restrict__ st0_in,
                                                   float* __restrict__ st0_out,
                                                   const float* __restrict__ st2_in,
                                                   float* __restrict__ st2_out,
                                                   int t0, int CH) {
    int bid = blockIdx.x;
    int b = bid >> 3, w = bid & 7;
    int ocStart = w * 9;
    int nOc = (w == 7) ? 7 : 9;
    int tid = threadIdx.x;
    __shared__ float v0[C1N], i0[C1N], z0[C1N];
    __shared__ float w2s[9 * 750];
    __shared__ float part[9 * 30 * 9];
    __shared__ float red[81];
    for (int e = tid; e < nOc * 750; e += 320) w2s[e] = w2[ocStart * 750 + e];
    float v2 = 0.f, i2 = 0.f;
    if (t0 == 0) {
        for (int e = tid; e < C1N; e += 320) { v0[e] = 0.f; i0[e] = 0.f; }
    } else {
        const float* s0 = st0_in + (size_t)b * 2 * C1N;
        for (int e = tid; e < C1N; e += 320) { v0[e] = s0[e]; i0[e] = s0[C1N + e]; }
        if (tid < nOc) {
            v2 = st2_in[b * ZSEQN + ocStart + tid];
            i2 = st2_in[BATCH * ZSEQN + b * ZSEQN + ocStart + tid];
        }
    }
    float bias2 = (tid < nOc) ? b2[ocStart + tid] : 0.f;
    __syncthreads();
    const float* c1b = c1buf + (size_t)b * CH * C1N;
    float* zs = zbuf + (size_t)b * TSTEPS * ZSEQN;
    int nConv = nOc * 30;
    for (int tc = 0; tc < CH; ++tc) {
        const float* c1t = c1b + (size_t)tc * C1N;
        for (int e = tid; e < C1N; e += 320) {
            float v = v0[e], i = i0[e];
            float vd = v + 0.1f * (i - v);
            float id = i - 0.2f * i;
            bool sp = (vd > 1.0f);
            v0[e] = sp ? 0.f : vd;
            i0[e] = id + c1t[e];
            z0[e] = sp ? 1.f : 0.f;
        }
        __syncthreads();
        if (tid < nConv) {
            int ol = tid / 30, ic = tid - ol * 30;
            float zw[49];
            #pragma unroll
            for (int j = 0; j < 49; ++j) zw[j] = z0[ic * 49 + j];
            float a[9];
            #pragma unroll
            for (int p = 0; p < 9; ++p) a[p] = 0.f;
            const float* wb = &w2s[ol * 750 + ic * 25];
            #pragma unroll
            for (int ky = 0; ky < 5; ++ky)
                #pragma unroll
                for (int kx = 0; kx < 5; ++kx) {
                    float wv = wb[ky * 5 + kx];
                    #pragma unroll
                    for (int cy = 0; cy < 3; ++cy)
                        #pragma unroll
                        for (int cx = 0; cx < 3; ++cx)
                            a[cy * 3 + cx] = fmaf(zw[(cy + ky) * 7 + cx + kx], wv, a[cy * 3 + cx]);
                }
            #pragma unroll
            for (int p = 0; p < 9; ++p) part[tid * 9 + p] = a[p];
        }
        __syncthreads();
        if (tid < nOc * 9) {
            int ol = tid / 9, pos = tid - ol * 9;
            float s = 0.f;
            for (int ic = 0; ic < 30; ++ic) s += part[(ol * 30 + ic) * 9 + pos];
            red[tid] = s;
        }
        __syncthreads();
        if (tid < nOc) {
            float m = -1e30f;
            #pragma unroll
            for (int p = 0; p < 9; ++p) m = fmaxf(m, red[tid * 9 + p]);
            float inp = m + bias2;
            float vd = v2 + 0.1f * (i2 - v2);
            float id = i2 - 0.2f * i2;
            bool sp = (vd > 1.0f);
            v2 = sp ? 0.f : vd;
            i2 = id + inp;
            zs[(size_t)(t0 + tc) * ZSEQN + ocStart + tid] = sp ? 1.f : 0.f;
        }
        __syncthreads();
    }
    if (w == 0) {
        float* s0 = st0_out + (size_t)b * 2 * C1N;
        for (int e = tid; e < C1N; e += 320) { s0[e] = v0[e]; s0[C1N + e] = i0[e]; }
    }
    if (tid < nOc) {
        st2_out[b * ZSEQN + ocStart + tid] = v2;
        st2_out[BATCH * ZSEQN + b * ZSEQN + ocStart + tid] = i2;
    }
}

// -------------------------------------------------------------------- K3 ---
__device__ __forceinline__ float4 f4add(float4 a, const float4 b) {
    a.x += b.x; a.y += b.y; a.z += b.z; a.w += b.w; return a;
}
__device__ __forceinline__ void ast64(unsigned long long* p, unsigned long long v) {
    __hip_atomic_store(p, v, __ATOMIC_RELAXED, __HIP_MEMORY_SCOPE_AGENT);
}
__device__ __forceinline__ unsigned long long ald64(const unsigned long long* p) {
    return __hip_atomic_load((unsigned long long*)p, __ATOMIC_RELAXED,
                             __HIP_MEMORY_SCOPE_AGENT);
}

// One 64-col stripe of one chain per WG (256 threads). Publishes its 64
// spike bits as two tagged u64s per step into the per-step archive.
template <int ROLE>
__device__ __forceinline__ void stripe_body(int b, int s,
        const float* __restrict__ zbuf,
        const float* __restrict__ catT,
        unsigned long long* __restrict__ arch) {   // this chain's archive
    constexpr int N   = ROLE ? HID2 : HID1;
    constexpr int K   = ROLE ? K2CAT : K1CAT;
    constexpr int SW  = N / 32;      // tagged words per step (== NW)
    constexpr int NW  = N / 32;
    constexpr int NWT = NW + 3;
    constexpr int N4  = N / 4;

    __shared__ float part[16 * 68];
    __shared__ unsigned short list[K2CAT];
    __shared__ unsigned int maskw[40];
    __shared__ unsigned int wprefix[40];

    const int t = threadIdx.x;
    const int lane = t & 63, wv = t >> 6;
    const int aid = t >> 4, qid = t & 15;    // 16 A-slices x 16 quads
    const int q0 = s * 16;

    const float* zsb = zbuf + (size_t)b * TSTEPS * ZSEQN;
    const float4* __restrict__ catT4 = (const float4*)catT;

    float v = 0.f, iacc = 0.f;

    // ---- initial list (step 0): rec bits zero, conv bits from zsb[0] ----
    if (t < NW) maskw[t] = 0u;
    {
        float zc = (t < 70) ? zsb[t] : 0.f;
        unsigned long long mc = __ballot(zc != 0.f);
        if (wv == 0 && lane == 0) { maskw[NW] = (unsigned)mc; maskw[NW + 1] = (unsigned)(mc >> 32); }
        if (wv == 1 && lane == 0) { maskw[NW + 2] = (unsigned)(mc & 0x3full); }
    }
    __syncthreads();
    if (wv == 0) {
        unsigned val = (lane < NWT) ? __popc(maskw[lane]) : 0u;
        #pragma unroll
        for (int d = 1; d < 64; d <<= 1) {
            unsigned u = __shfl_up(val, d);
            if (lane >= d) val += u;
        }
        if (lane < NWT) wprefix[lane + 1] = val;
        if (lane == 0) wprefix[0] = 0u;
    }
    __syncthreads();
    int A = wprefix[NWT];
    for (int jj = t; jj < K; jj += 256) {
        unsigned m = maskw[jj >> 5];
        if ((m >> (jj & 31)) & 1u)
            list[wprefix[jj >> 5] + __popc(m & ((1u << (jj & 31)) - 1u))] = (unsigned short)jj;
    }
    __syncthreads();

    for (int tt = 0; tt < TSTEPS; ++tt) {
        float znext = (t < 70 && tt + 1 < TSTEPS) ? zsb[(size_t)(tt + 1) * ZSEQN + t] : 0.f;
        // ---- gather active rows, 64 cols (16 quads), 16 slices, ILP4 ----
        float4 s0 = {0.f, 0.f, 0.f, 0.f}, s1 = s0, s2 = s0, s3 = s0;
        int idx = aid;
        for (; idx + 48 < A; idx += 64) {
            s0 = f4add(s0, catT4[(size_t)list[idx]      * N4 + q0 + qid]);
            s1 = f4add(s1, catT4[(size_t)list[idx + 16] * N4 + q0 + qid]);
            s2 = f4add(s2, catT4[(size_t)list[idx + 32] * N4 + q0 + qid]);
            s3 = f4add(s3, catT4[(size_t)list[idx + 48] * N4 + q0 + qid]);
        }
        for (; idx < A; idx += 16) s0 = f4add(s0, catT4[(size_t)list[idx] * N4 + q0 + qid]);
        s0 = f4add(f4add(s0, s1), f4add(s2, s3));
        *(float4*)(part + aid * 68 + 4 * qid) = s0;
        __syncthreads();                                   // B1: part ready
        // ---- state update: thread t<64 owns col s*64+t (all wave 0) ----
        float znew = 0.f;
        if (t < 64) {
            float cur = 0.f;
            #pragma unroll
            for (int a = 0; a < 16; ++a) cur += part[a * 68 + t];
            float vd = v + 0.1f * (iacc - v);
            float id = iacc - 0.2f * iacc;
            bool sp = (vd > 0.4f);
            znew = sp ? 1.f : 0.f;
            v = sp ? 0.f : vd;
            iacc = id + cur;
        }
        unsigned long long mz = __ballot(znew != 0.f);     // wave0: all 64 cols
        if (wv == 0 && lane == 0) {
            unsigned long long tag = ((unsigned long long)(tt + 1)) << 32;
            ast64(arch + (size_t)tt * SW + s * 2,     tag | (unsigned)(mz & 0xffffffffull));
            ast64(arch + (size_t)tt * SW + s * 2 + 1, tag | (unsigned)(mz >> 32));
        }
        {   // conv bits for next step's list
            unsigned long long mc = __ballot(znext != 0.f);
            if (wv == 0 && lane == 0) { maskw[NW] = (unsigned)mc; maskw[NW + 1] = (unsigned)(mc >> 32); }
            if (wv == 1 && lane == 0) { maskw[NW + 2] = (unsigned)(mc & 0x3full); }
        }
        __syncthreads();                                   // B2: conv words in LDS
        // ---- wave0: poll all stripes' tagged masks, then prefix-scan ----
        if (wv == 0) {
            bool need = lane < SW;
            unsigned long long w = 0;
            for (;;) {
                if (need) w = ald64(arch + (size_t)tt * SW + lane);
                bool ok = !need || (unsigned)(w >> 32) == (unsigned)(tt + 1);
                if (__ballot(ok) == ~0ull) break;
                __builtin_amdgcn_s_sleep(1);
            }
            if (need) maskw[lane] = (unsigned)w;
            unsigned val = need ? __popc((unsigned)w)
                                : ((lane < NWT) ? __popc(maskw[lane]) : 0u);
            #pragma unroll
            for (int d = 1; d < 64; d <<= 1) {
                unsigned u = __shfl_up(val, d);
                if (lane >= d) val += u;
            }
            if (lane < NWT) wprefix[lane + 1] = val;
            if (lane == 0) wprefix[0] = 0u;
        }
        __syncthreads();                                   // B3: maskw/wprefix
        A = wprefix[NWT];
        for (int jj = t; jj < K; jj += 256) {
            unsigned m = maskw[jj >> 5];
            if ((m >> (jj & 31)) & 1u)
                list[wprefix[jj >> 5] + __popc(m & ((1u << (jj & 31)) - 1u))] = (unsigned short)jj;
        }
        __syncthreads();                                   // B4: list ready
    }
}

// Reader WG: trails the archive, computes fc readout + LI chain + final out.
template <int ROLE>
__device__ __forceinline__ void readout_body(int b,
        const float* __restrict__ fcw,
        const unsigned long long* __restrict__ arch,
        float* __restrict__ out) {
    constexpr int N  = ROLE ? HID2 : HID1;
    constexpr int SW = N / 32;
    constexpr int R  = ROLE ? 10 : 4;

    __shared__ unsigned int zw[32];
    __shared__ float wpart[40];
    __shared__ float mvals[10];

    const int t = threadIdx.x;
    const int lane = t & 63, wv = t >> 6;
    float vli = 0.f, ili = 0.f, rmax = -1e30f;

    for (int tt = 0; tt < TSTEPS; ++tt) {
        if (wv == 0) {
            bool need = lane < SW;
            unsigned long long w = 0;
            for (;;) {
                if (need) w = ald64(arch + (size_t)tt * SW + lane);
                bool ok = !need || (unsigned)(w >> 32) == (unsigned)(tt + 1);
                if (__ballot(ok) == ~0ull) break;
                __builtin_amdgcn_s_sleep(1);
            }
            if (need) zw[lane] = (unsigned)w;
        }
        __syncthreads();                                   // zw ready
        #pragma unroll
        for (int k = 0; k < R; ++k) {
            float p;
            if (ROLE) {
                unsigned bits = (zw[(t * 4) >> 5] >> ((t * 4) & 31)) & 0xFu;
                float4 w4 = ((const float4*)fcw)[k * (N / 4) + t];
                p = (bits & 1u ? w4.x : 0.f) + (bits & 2u ? w4.y : 0.f)
                  + (bits & 4u ? w4.z : 0.f) + (bits & 8u ? w4.w : 0.f);
            } else {
                unsigned bits = (zw[(t * 2) >> 5] >> ((t * 2) & 31)) & 0x3u;
                float2 w2 = ((const float2*)fcw)[k * (N / 2) + t];
                p = (bits & 1u ? w2.x : 0.f) + (bits & 2u ? w2.y : 0.f);
            }
            #pragma unroll
            for (int off = 32; off; off >>= 1) p += __shfl_xor(p, off);
            if (lane == 0) wpart[k * 4 + wv] = p;
        }
        __syncthreads();                                   // wpart ready
        if (t < R) {
            float inp = wpart[t * 4] + wpart[t * 4 + 1] + wpart[t * 4 + 2] + wpart[t * 4 + 3];
            float vn = vli + 0.1f * (ili - vli);
            ili = ili - 0.2f * ili + inp;
            vli = vn;
            rmax = fmaxf(rmax, vn);
        }
        // wave0's next poll follows its own LI read in program order; other
        // waves can't write wpart again until after the next zw barrier.
    }
    if (ROLE) {
        if (t < 10) mvals[t] = rmax;
        __syncthreads();
        if (t < 10) {
            float M = -1e30f;
            #pragma unroll
            for (int k = 0; k < 10; ++k) M = fmaxf(M, mvals[k]);
            float ssum = 0.f;
            #pragma unroll
            for (int k = 0; k < 10; ++k) ssum += expf(mvals[k] - M);
            out[BATCH * 4 + b * 10 + t] = mvals[t] - M - logf(ssum);
        }
    } else if (t < 4) {
        out[b * 4 + t] = rmax;
    }
}

__global__ __launch_bounds__(256) void rec_tagged(const float* __restrict__ fc_out_w,
                                                  const float* __restrict__ cl_fc_w,
                                                  const float* __restrict__ zbuf,
                                                  const float* __restrict__ w1t,
                                                  const float* __restrict__ w2t,
                                                  unsigned long long* __restrict__ arch1,
                                                  unsigned long long* __restrict__ arch0,
                                                  float* __restrict__ out) {
    int bid = blockIdx.x;
    if (bid < 512) {                       // role-1 stripes: bid%8 == s%8
        int b = bid >> 4, s = bid & 15;
        stripe_body<1>(b, s, zbuf, w2t, arch1 + (size_t)b * TSTEPS * 32);
    } else if (bid < 768) {                // role-0 stripes: bid%8 == s
        int idx = bid - 512;
        int b = idx >> 3, s = idx & 7;
        stripe_body<0>(b, s, zbuf, w1t, arch0 + (size_t)b * TSTEPS * 16);
    } else if (bid < 800) {
        int b = bid - 768;
        readout_body<1>(b, cl_fc_w, arch1 + (size_t)b * TSTEPS * 32, out);
    } else {
        int b = bid - 800;
        readout_body<0>(b, fc_out_w, arch0 + (size_t)b * TSTEPS * 16, out);
    }
}

// ---------------------------------------------------------------------------
extern "C" void kernel_launch(void* const* d_in, const int* in_sizes, int n_in,
                              void* d_out, int out_size, void* d_ws, size_t ws_size,
                              hipStream_t stream) {
    const float* x        = (const float*)d_in[0];
    const float* w1       = (const float*)d_in[1];
    const float* b1       = (const float*)d_in[2];
    const float* w2       = (const float*)d_in[3];
    const float* b2       = (const float*)d_in[4];
    const float* l1_in_w  = (const float*)d_in[5];
    const float* l1_rec_w = (const float*)d_in[6];
    const float* fc_out_w = (const float*)d_in[7];
    const float* cl_in_w  = (const float*)d_in[8];
    const float* cl_rec_w = (const float*)d_in[9];
    const float* cl_fc_w  = (const float*)d_in[10];
    float* out = (float*)d_out;
    float* ws  = (float*)d_ws;

    size_t base = (size_t)N_Z + N_W1T + N_W2T + N_ARCH_F + 2 * (N_ST0 + N_ST2);
    size_t avail = ws_size / 4;
    static const int divs[] = {150, 75, 50, 30, 25, 15, 10, 6, 5, 3, 2, 1};
    int CH = 1;
    for (int i = 0; i < 12; ++i) {
        size_t need = base + (size_t)BATCH * divs[i] * C1N;
        if (need <= avail) { CH = divs[i]; break; }
    }
    float* zbuf = ws;
    float* w1t  = zbuf + N_Z;
    float* w2t  = w1t + N_W1T;
    unsigned long long* arch1 = (unsigned long long*)(w2t + N_W2T);
    unsigned long long* arch0 = arch1 + A1_U64;
    float* st0a = (float*)(arch0 + A0_U64);
    float* st0b = st0a + N_ST0;
    float* st2a = st0b + N_ST0;
    float* st2b = st2a + N_ST2;
    float* c1buf = st2b + N_ST2;

    prep_weights<<<dim3(512), dim3(256), 0, stream>>>(l1_in_w, l1_rec_w,
                                                      cl_in_w, cl_rec_w, w1t, w2t);
    init_arch<<<dim3(64), dim3(256), 0, stream>>>(arch1);
    int nChunks = TSTEPS / CH;
    for (int c = 0; c < nChunks; ++c) {
        int t0 = c * CH;
        int par = c & 1;
        const float* s0i = par ? st0b : st0a;
        float*       s0o = par ? st0a : st0b;
        const float* s2i = par ? st2b : st2a;
        float*       s2o = par ? st2a : st2b;
        conv1_pool<<<dim3(BATCH * CH), dim3(640), 0, stream>>>(x, w1, b1, c1buf, t0, CH);
        conv2_chain<<<dim3(256), dim3(320), 0, stream>>>(w2, b2, c1buf, zbuf,
                                                         s0i, s0o, s2i, s2o, t0, CH);
    }
    rec_tagged<<<dim3(832), dim3(256), 0, stream>>>(fc_out_w, cl_fc_w, zbuf,
                                                    w1t, w2t, arch1, arch0, out);
}

// Round 8
// 1078.162 us; speedup vs baseline: 2.2360x; 1.1908x over previous
//
#include <hip/hip_runtime.h>
#include <math.h>

// ---------------------------------------------------------------------------
// SNN forward. Round-8: early-publish rec. The LIF spike z(t) depends only
// on state from t-1, not on this step's gather -> publish the tagged spike
// mask at the TOP of the iteration, so LLC visibility overlaps the gather
// and the poll (after gather+reduce) succeeds first try. 3 barriers/step.
// Round-7 (tagged u64 archive, write-once, relaxed atomics) kept unchanged.
// ---------------------------------------------------------------------------

#define BATCH 32
#define TSTEPS 150
#define C1N 1470            // 30*7*7 (trimmed: pooled conv2 only needs 7x7)
#define ZSEQN 70
#define HID1 512
#define HID2 1024
#define K1CAT 582           // rows: [rec(512) | conv(70)]
#define K2CAT 1094          // rows: [rec(1024) | conv(70)]

#define N_Z    (BATCH*TSTEPS*ZSEQN)   // 336,000
#define N_W1T  (K1CAT*HID1)           // 297,984
#define N_W2T  (K2CAT*HID2)           // 1,120,256
#define N_ST0  (BATCH*2*C1N)          // 94,080
#define N_ST2  (BATCH*2*ZSEQN)        // 4,480

// mask archive (u64): role1 [b][tt][32 words], role0 [b][tt][16 words]
#define A1_U64 (BATCH*TSTEPS*32)      // 153,600
#define A0_U64 (BATCH*TSTEPS*16)      // 76,800
#define N_ARCH_F ((A1_U64+A0_U64)*2)  // float-equivalents = 460,800 (1.84 MB)

// -------------------------------------------------------------------- K0 ---
__global__ void prep_weights(const float* __restrict__ l1_in_w,
                             const float* __restrict__ l1_rec_w,
                             const float* __restrict__ cl_in_w,
                             const float* __restrict__ cl_rec_w,
                             float* __restrict__ w1t,
                             float* __restrict__ w2t) {
    int idx = blockIdx.x * blockDim.x + threadIdx.x;
    int stride = gridDim.x * blockDim.x;
    for (int e = idx; e < N_W1T; e += stride) {
        int j = e / HID1, o = e - j * HID1;
        w1t[e] = (j < HID1) ? l1_rec_w[o * HID1 + j] : l1_in_w[o * 70 + (j - HID1)];
    }
    for (int e = idx; e < N_W2T; e += stride) {
        int j = e / HID2, o = e - j * HID2;
        w2t[e] = (j < HID2) ? cl_rec_w[o * HID2 + j] : cl_in_w[o * 70 + (j - HID2)];
    }
}

__global__ void init_arch(unsigned long long* __restrict__ arch) {
    size_t idx = (size_t)blockIdx.x * blockDim.x + threadIdx.x;
    size_t stride = (size_t)gridDim.x * blockDim.x;
    for (size_t e = idx; e < (A1_U64 + A0_U64); e += stride) arch[e] = 0ull;
}

// -------------------------------------------------------------------- K1 ---
__global__ __launch_bounds__(640) void conv1_pool(const float* __restrict__ x,
                                                  const float* __restrict__ w1,
                                                  const float* __restrict__ b1,
                                                  float* __restrict__ c1buf,
                                                  int t0, int CH) {
    __shared__ float img[2 * 34 * 34];
    __shared__ float w1s[30 * 2 * 49];
    __shared__ float crow[630 * 21];
    int bid = blockIdx.x;
    int b = bid / CH, tc = bid - b * CH;
    int t = t0 + tc;
    int tid = threadIdx.x;
    const float* xin = x + (size_t)(b * TSTEPS + t) * 2312;
    for (int e = tid; e < 2312; e += 640) img[e] = xin[e];
    for (int e = tid; e < 2940; e += 640) w1s[e] = w1[e];
    __syncthreads();
    if (tid < 630) {
        int oc = tid / 21, cy = tid - oc * 21;
        float acc[21];
        #pragma unroll
        for (int j = 0; j < 21; ++j) acc[j] = 0.f;
        #pragma unroll
        for (int ic = 0; ic < 2; ++ic) {
            const float* irow0 = &img[ic * 1156];
            const float* wrow = &w1s[(oc * 2 + ic) * 49];
            #pragma unroll
            for (int ky = 0; ky < 7; ++ky) {
                const float* ir = &irow0[(cy + ky) * 34];
                float r[27];
                #pragma unroll
                for (int j = 0; j < 27; ++j) r[j] = ir[j];
                #pragma unroll
                for (int kx = 0; kx < 7; ++kx) {
                    float w = wrow[ky * 7 + kx];
                    #pragma unroll
                    for (int cx = 0; cx < 21; ++cx)
                        acc[cx] = fmaf(r[cx + kx], w, acc[cx]);
                }
            }
        }
        #pragma unroll
        for (int cx = 0; cx < 21; ++cx) crow[tid * 21 + cx] = acc[cx];
    }
    __syncthreads();
    float* c1 = c1buf + (size_t)bid * C1N;
    for (int p = tid; p < C1N; p += 640) {
        int oc = p / 49; int r = p - oc * 49; int py = r / 7, px = r - py * 7;
        float m = -1e30f;
        #pragma unroll
        for (int dy = 0; dy < 3; ++dy) {
            int rowid = oc * 21 + 3 * py + dy;
            #pragma unroll
            for (int dx = 0; dx < 3; ++dx)
                m = fmaxf(m, crow[rowid * 21 + 3 * px + dx]);
        }
        c1[p] = m + b1[oc];
    }
}

// -------------------------------------------------------------------- K2 ---
__global__ __launch_bounds__(320) void conv2_chain(const float* __restrict__ w2,
                                                   const float* __restrict__ b2,
                                                   const float* __restrict__ c1buf,
                                                   float* __restrict__ zbuf,
                                                   const float* __restrict__ st0_in,
                                                   float* __restrict__ st0_out,
                                                   const float* __restrict__ st2_in,
                                                   float* __restrict__ st2_out,
                                                   int t0, int CH) {
    int bid = blockIdx.x;
    int b = bid >> 3, w = bid & 7;
    int ocStart = w * 9;
    int nOc = (w == 7) ? 7 : 9;
    int tid = threadIdx.x;
    __shared__ float v0[C1N], i0[C1N], z0[C1N];
    __shared__ float w2s[9 * 750];
    __shared__ float part[9 * 30 * 9];
    __shared__ float red[81];
    for (int e = tid; e < nOc * 750; e += 320) w2s[e] = w2[ocStart * 750 + e];
    float v2 = 0.f, i2 = 0.f;
    if (t0 == 0) {
        for (int e = tid; e < C1N; e += 320) { v0[e] = 0.f; i0[e] = 0.f; }
    } else {
        const float* s0 = st0_in + (size_t)b * 2 * C1N;
        for (int e = tid; e < C1N; e += 320) { v0[e] = s0[e]; i0[e] = s0[C1N + e]; }
        if (tid < nOc) {
            v2 = st2_in[b * ZSEQN + ocStart + tid];
            i2 = st2_in[BATCH * ZSEQN + b * ZSEQN + ocStart + tid];
        }
    }
    float bias2 = (tid < nOc) ? b2[ocStart + tid] : 0.f;
    __syncthreads();
    const float* c1b = c1buf + (size_t)b * CH * C1N;
    float* zs = zbuf + (size_t)b * TSTEPS * ZSEQN;
    int nConv = nOc * 30;
    for (int tc = 0; tc < CH; ++tc) {
        const float* c1t = c1b + (size_t)tc * C1N;
        for (int e = tid; e < C1N; e += 320) {
            float v = v0[e], i = i0[e];
            float vd = v + 0.1f * (i - v);
            float id = i - 0.2f * i;
            bool sp = (vd > 1.0f);
            v0[e] = sp ? 0.f : vd;
            i0[e] = id + c1t[e];
            z0[e] = sp ? 1.f : 0.f;
        }
        __syncthreads();
        if (tid < nConv) {
            int ol = tid / 30, ic = tid - ol * 30;
            float zw[49];
            #pragma unroll
            for (int j = 0; j < 49; ++j) zw[j] = z0[ic * 49 + j];
            float a[9];
            #pragma unroll
            for (int p = 0; p < 9; ++p) a[p] = 0.f;
            const float* wb = &w2s[ol * 750 + ic * 25];
            #pragma unroll
            for (int ky = 0; ky < 5; ++ky)
                #pragma unroll
                for (int kx = 0; kx < 5; ++kx) {
                    float wv = wb[ky * 5 + kx];
                    #pragma unroll
                    for (int cy = 0; cy < 3; ++cy)
                        #pragma unroll
                        for (int cx = 0; cx < 3; ++cx)
                            a[cy * 3 + cx] = fmaf(zw[(cy + ky) * 7 + cx + kx], wv, a[cy * 3 + cx]);
                }
            #pragma unroll
            for (int p = 0; p < 9; ++p) part[tid * 9 + p] = a[p];
        }
        __syncthreads();
        if (tid < nOc * 9) {
            int ol = tid / 9, pos = tid - ol * 9;
            float s = 0.f;
            for (int ic = 0; ic < 30; ++ic) s += part[(ol * 30 + ic) * 9 + pos];
            red[tid] = s;
        }
        __syncthreads();
        if (tid < nOc) {
            float m = -1e30f;
            #pragma unroll
            for (int p = 0; p < 9; ++p) m = fmaxf(m, red[tid * 9 + p]);
            float inp = m + bias2;
            float vd = v2 + 0.1f * (i2 - v2);
            float id = i2 - 0.2f * i2;
            bool sp = (vd > 1.0f);
            v2 = sp ? 0.f : vd;
            i2 = id + inp;
            zs[(size_t)(t0 + tc) * ZSEQN + ocStart + tid] = sp ? 1.f : 0.f;
        }
        __syncthreads();
    }
    if (w == 0) {
        float* s0 = st0_out + (size_t)b * 2 * C1N;
        for (int e = tid; e < C1N; e += 320) { s0[e] = v0[e]; s0[C1N + e] = i0[e]; }
    }
    if (tid < nOc) {
        st2_out[b * ZSEQN + ocStart + tid] = v2;
        st2_out[BATCH * ZSEQN + b * ZSEQN + ocStart + tid] = i2;
    }
}

// -------------------------------------------------------------------- K3 ---
__device__ __forceinline__ float4 f4add(float4 a, const float4 b) {
    a.x += b.x; a.y += b.y; a.z += b.z; a.w += b.w; return a;
}
__device__ __forceinline__ void ast64(unsigned long long* p, unsigned long long v) {
    __hip_atomic_store(p, v, __ATOMIC_RELAXED, __HIP_MEMORY_SCOPE_AGENT);
}
__device__ __forceinline__ unsigned long long ald64(const unsigned long long* p) {
    return __hip_atomic_load((unsigned long long*)p, __ATOMIC_RELAXED,
                             __HIP_MEMORY_SCOPE_AGENT);
}

// One 64-col stripe of one chain per WG (256 threads).
// Per iteration tt: publish z(tt) FIRST (depends only on prior state),
// then gather cur(tt) (overlapping publish visibility), then poll peers.
template <int ROLE>
__device__ __forceinline__ void stripe_body(int b, int s,
        const float* __restrict__ zbuf,
        const float* __restrict__ catT,
        unsigned long long* __restrict__ arch) {   // this chain's archive
    constexpr int N   = ROLE ? HID2 : HID1;
    constexpr int K   = ROLE ? K2CAT : K1CAT;
    constexpr int SW  = N / 32;      // tagged words per step (== NW)
    constexpr int NW  = N / 32;
    constexpr int NWT = NW + 3;
    constexpr int N4  = N / 4;

    __shared__ float part[16 * 68];
    __shared__ unsigned short list[K2CAT];
    __shared__ unsigned int maskw[40];
    __shared__ unsigned int wprefix[40];

    const int t = threadIdx.x;
    const int lane = t & 63, wv = t >> 6;
    const int aid = t >> 4, qid = t & 15;    // 16 A-slices x 16 quads
    const int q0 = s * 16;

    const float* zsb = zbuf + (size_t)b * TSTEPS * ZSEQN;
    const float4* __restrict__ catT4 = (const float4*)catT;

    float v = 0.f, iacc = 0.f;

    // ---- initial list (step 0): rec bits zero, conv bits from zsb[0] ----
    if (t < NW) maskw[t] = 0u;
    {
        float zc = (t < 70) ? zsb[t] : 0.f;
        unsigned long long mc = __ballot(zc != 0.f);
        if (wv == 0 && lane == 0) { maskw[NW] = (unsigned)mc; maskw[NW + 1] = (unsigned)(mc >> 32); }
        if (wv == 1 && lane == 0) { maskw[NW + 2] = (unsigned)(mc & 0x3full); }
    }
    __syncthreads();
    if (wv == 0) {
        unsigned val = (lane < NWT) ? __popc(maskw[lane]) : 0u;
        #pragma unroll
        for (int d = 1; d < 64; d <<= 1) {
            unsigned u = __shfl_up(val, d);
            if (lane >= d) val += u;
        }
        if (lane < NWT) wprefix[lane + 1] = val;
        if (lane == 0) wprefix[0] = 0u;
    }
    __syncthreads();
    int A = wprefix[NWT];
    for (int jj = t; jj < K; jj += 256) {
        unsigned m = maskw[jj >> 5];
        if ((m >> (jj & 31)) & 1u)
            list[wprefix[jj >> 5] + __popc(m & ((1u << (jj & 31)) - 1u))] = (unsigned short)jj;
    }
    __syncthreads();

    // conv spikes for step 1's list (used at top of iteration 0)
    float znext = (t < 70 && 1 < TSTEPS) ? zsb[(size_t)1 * ZSEQN + t] : 0.f;

    for (int tt = 0; tt < TSTEPS; ++tt) {
        // ---- TOP: spike decision + publish (state from step tt-1 only) ----
        float vd = v + 0.1f * (iacc - v);
        bool sp = (t < 64) && (vd > 0.4f);
        float znew = sp ? 1.f : 0.f;
        if (t < 64) v = sp ? 0.f : vd;
        unsigned long long mz = __ballot(znew != 0.f);     // wave0 = all 64 cols
        if (wv == 0 && lane == 0) {
            unsigned long long tag = ((unsigned long long)(tt + 1)) << 32;
            ast64(arch + (size_t)tt * SW + s * 2,     tag | (unsigned)(mz & 0xffffffffull));
            ast64(arch + (size_t)tt * SW + s * 2 + 1, tag | (unsigned)(mz >> 32));
        }
        {   // conv bits zc(tt+1) for the next list (znext preloaded)
            unsigned long long mc = __ballot(znext != 0.f);
            if (wv == 0 && lane == 0) { maskw[NW] = (unsigned)mc; maskw[NW + 1] = (unsigned)(mc >> 32); }
            if (wv == 1 && lane == 0) { maskw[NW + 2] = (unsigned)(mc & 0x3full); }
        }
        // prefetch conv spikes for the following iteration
        znext = (t < 70 && tt + 2 < TSTEPS) ? zsb[(size_t)(tt + 2) * ZSEQN + t] : 0.f;
        // ---- gather active rows (list built from z(tt-1) + zc(tt)) ----
        float4 s0 = {0.f, 0.f, 0.f, 0.f}, s1 = s0, s2 = s0, s3 = s0;
        int idx = aid;
        for (; idx + 48 < A; idx += 64) {
            s0 = f4add(s0, catT4[(size_t)list[idx]      * N4 + q0 + qid]);
            s1 = f4add(s1, catT4[(size_t)list[idx + 16] * N4 + q0 + qid]);
            s2 = f4add(s2, catT4[(size_t)list[idx + 32] * N4 + q0 + qid]);
            s3 = f4add(s3, catT4[(size_t)list[idx + 48] * N4 + q0 + qid]);
        }
        for (; idx < A; idx += 16) s0 = f4add(s0, catT4[(size_t)list[idx] * N4 + q0 + qid]);
        s0 = f4add(f4add(s0, s1), f4add(s2, s3));
        *(float4*)(part + aid * 68 + 4 * qid) = s0;
        __syncthreads();                                   // B1: part + top LDS writes
        if (t < 64) {
            float cur = 0.f;
            #pragma unroll
            for (int a = 0; a < 16; ++a) cur += part[a * 68 + t];
            iacc = iacc - 0.2f * iacc + cur;
        }
        if (tt + 1 >= TSTEPS) break;                       // last step: no next list
        // ---- wave0: poll peers' z(tt) masks (in flight since TOP) ----
        if (wv == 0) {
            bool need = lane < SW;
            unsigned long long w = 0;
            for (;;) {
                if (need) w = ald64(arch + (size_t)tt * SW + lane);
                bool ok = !need || (unsigned)(w >> 32) == (unsigned)(tt + 1);
                if (__ballot(ok) == ~0ull) break;
                __builtin_amdgcn_s_sleep(1);
            }
            if (need) maskw[lane] = (unsigned)w;
            unsigned val = need ? __popc((unsigned)w)
                                : ((lane < NWT) ? __popc(maskw[lane]) : 0u);
            #pragma unroll
            for (int d = 1; d < 64; d <<= 1) {
                unsigned u = __shfl_up(val, d);
                if (lane >= d) val += u;
            }
            if (lane < NWT) wprefix[lane + 1] = val;
            if (lane == 0) wprefix[0] = 0u;
        }
        __syncthreads();                                   // B2: maskw/wprefix
        A = wprefix[NWT];
        for (int jj = t; jj < K; jj += 256) {
            unsigned m = maskw[jj >> 5];
            if ((m >> (jj & 31)) & 1u)
                list[wprefix[jj >> 5] + __popc(m & ((1u << (jj & 31)) - 1u))] = (unsigned short)jj;
        }
        __syncthreads();                                   // B3: list ready
    }
}

// Reader WG: trails the archive, computes fc readout + LI chain + final out.
template <int ROLE>
__device__ __forceinline__ void readout_body(int b,
        const float* __restrict__ fcw,
        const unsigned long long* __restrict__ arch,
        float* __restrict__ out) {
    constexpr int N  = ROLE ? HID2 : HID1;
    constexpr int SW = N / 32;
    constexpr int R  = ROLE ? 10 : 4;

    __shared__ unsigned int zw[32];
    __shared__ float wpart[40];
    __shared__ float mvals[10];

    const int t = threadIdx.x;
    const int lane = t & 63, wv = t >> 6;
    float vli = 0.f, ili = 0.f, rmax = -1e30f;

    for (int tt = 0; tt < TSTEPS; ++tt) {
        if (wv == 0) {
            bool need = lane < SW;
            unsigned long long w = 0;
            for (;;) {
                if (need) w = ald64(arch + (size_t)tt * SW + lane);
                bool ok = !need || (unsigned)(w >> 32) == (unsigned)(tt + 1);
                if (__ballot(ok) == ~0ull) break;
                __builtin_amdgcn_s_sleep(1);
            }
            if (need) zw[lane] = (unsigned)w;
        }
        __syncthreads();                                   // zw ready
        #pragma unroll
        for (int k = 0; k < R; ++k) {
            float p;
            if (ROLE) {
                unsigned bits = (zw[(t * 4) >> 5] >> ((t * 4) & 31)) & 0xFu;
                float4 w4 = ((const float4*)fcw)[k * (N / 4) + t];
                p = (bits & 1u ? w4.x : 0.f) + (bits & 2u ? w4.y : 0.f)
                  + (bits & 4u ? w4.z : 0.f) + (bits & 8u ? w4.w : 0.f);
            } else {
                unsigned bits = (zw[(t * 2) >> 5] >> ((t * 2) & 31)) & 0x3u;
                float2 w2 = ((const float2*)fcw)[k * (N / 2) + t];
                p = (bits & 1u ? w2.x : 0.f) + (bits & 2u ? w2.y : 0.f);
            }
            #pragma unroll
            for (int off = 32; off; off >>= 1) p += __shfl_xor(p, off);
            if (lane == 0) wpart[k * 4 + wv] = p;
        }
        __syncthreads();                                   // wpart ready
        if (t < R) {
            float inp = wpart[t * 4] + wpart[t * 4 + 1] + wpart[t * 4 + 2] + wpart[t * 4 + 3];
            float vn = vli + 0.1f * (ili - vli);
            ili = ili - 0.2f * ili + inp;
            vli = vn;
            rmax = fmaxf(rmax, vn);
        }
    }
    if (ROLE) {
        if (t < 10) mvals[t] = rmax;
        __syncthreads();
        if (t < 10) {
            float M = -1e30f;
            #pragma unroll
            for (int k = 0; k < 10; ++k) M = fmaxf(M, mvals[k]);
            float ssum = 0.f;
            #pragma unroll
            for (int k = 0; k < 10; ++k) ssum += expf(mvals[k] - M);
            out[BATCH * 4 + b * 10 + t] = mvals[t] - M - logf(ssum);
        }
    } else if (t < 4) {
        out[b * 4 + t] = rmax;
    }
}

__global__ __launch_bounds__(256) void rec_tagged(const float* __restrict__ fc_out_w,
                                                  const float* __restrict__ cl_fc_w,
                                                  const float* __restrict__ zbuf,
                                                  const float* __restrict__ w1t,
                                                  const float* __restrict__ w2t,
                                                  unsigned long long* __restrict__ arch1,
                                                  unsigned long long* __restrict__ arch0,
                                                  float* __restrict__ out) {
    int bid = blockIdx.x;
    if (bid < 512) {                       // role-1 stripes: bid%8 == s%8
        int b = bid >> 4, s = bid & 15;
        stripe_body<1>(b, s, zbuf, w2t, arch1 + (size_t)b * TSTEPS * 32);
    } else if (bid < 768) {                // role-0 stripes: bid%8 == s
        int idx = bid - 512;
        int b = idx >> 3, s = idx & 7;
        stripe_body<0>(b, s, zbuf, w1t, arch0 + (size_t)b * TSTEPS * 16);
    } else if (bid < 800) {
        int b = bid - 768;
        readout_body<1>(b, cl_fc_w, arch1 + (size_t)b * TSTEPS * 32, out);
    } else {
        int b = bid - 800;
        readout_body<0>(b, fc_out_w, arch0 + (size_t)b * TSTEPS * 16, out);
    }
}

// ---------------------------------------------------------------------------
extern "C" void kernel_launch(void* const* d_in, const int* in_sizes, int n_in,
                              void* d_out, int out_size, void* d_ws, size_t ws_size,
                              hipStream_t stream) {
    const float* x        = (const float*)d_in[0];
    const float* w1       = (const float*)d_in[1];
    const float* b1       = (const float*)d_in[2];
    const float* w2       = (const float*)d_in[3];
    const float* b2       = (const float*)d_in[4];
    const float* l1_in_w  = (const float*)d_in[5];
    const float* l1_rec_w = (const float*)d_in[6];
    const float* fc_out_w = (const float*)d_in[7];
    const float* cl_in_w  = (const float*)d_in[8];
    const float* cl_rec_w = (const float*)d_in[9];
    const float* cl_fc_w  = (const float*)d_in[10];
    float* out = (float*)d_out;
    float* ws  = (float*)d_ws;

    size_t base = (size_t)N_Z + N_W1T + N_W2T + N_ARCH_F + 2 * (N_ST0 + N_ST2);
    size_t avail = ws_size / 4;
    static const int divs[] = {150, 75, 50, 30, 25, 15, 10, 6, 5, 3, 2, 1};
    int CH = 1;
    for (int i = 0; i < 12; ++i) {
        size_t need = base + (size_t)BATCH * divs[i] * C1N;
        if (need <= avail) { CH = divs[i]; break; }
    }
    float* zbuf = ws;
    float* w1t  = zbuf + N_Z;
    float* w2t  = w1t + N_W1T;
    unsigned long long* arch1 = (unsigned long long*)(w2t + N_W2T);
    unsigned long long* arch0 = arch1 + A1_U64;
    float* st0a = (float*)(arch0 + A0_U64);
    float* st0b = st0a + N_ST0;
    float* st2a = st0b + N_ST0;
    float* st2b = st2a + N_ST2;
    float* c1buf = st2b + N_ST2;

    prep_weights<<<dim3(512), dim3(256), 0, stream>>>(l1_in_w, l1_rec_w,
                                                      cl_in_w, cl_rec_w, w1t, w2t);
    init_arch<<<dim3(64), dim3(256), 0, stream>>>(arch1);
    int nChunks = TSTEPS / CH;
    for (int c = 0; c < nChunks; ++c) {
        int t0 = c * CH;
        int par = c & 1;
        const float* s0i = par ? st0b : st0a;
        float*       s0o = par ? st0a : st0b;
        const float* s2i = par ? st2b : st2a;
        float*       s2o = par ? st2a : st2b;
        conv1_pool<<<dim3(BATCH * CH), dim3(640), 0, stream>>>(x, w1, b1, c1buf, t0, CH);
        conv2_chain<<<dim3(256), dim3(320), 0, stream>>>(w2, b2, c1buf, zbuf,
                                                         s0i, s0o, s2i, s2o, t0, CH);
    }
    rec_tagged<<<dim3(832), dim3(256), 0, stream>>>(fc_out_w, cl_fc_w, zbuf,
                                                    w1t, w2t, arch1, arch0, out);
}

// Round 9
// 934.669 us; speedup vs baseline: 2.5792x; 1.1535x over previous
//
#include <hip/hip_runtime.h>
#include <math.h>

// ---------------------------------------------------------------------------
// SNN forward. Round-9: conv2_chain overhaul —
//  (a) bid = w*32+b so all 8 WGs of a batch share one XCD (c1 fetched from
//      HBM once per XCD, 7 L2 hits) — round-8 profile showed 110MB FETCH
//      for a 28MB buffer (8 XCDs each streaming it);
//  (b) double-buffered LDS c1 tile with register prefetch issued one step
//      ahead (fetch latency hides under conv compute);
//  (c) lif0 v/i state in registers (5 elems/thread);
//  (d) 3 barriers/step (was 6).
// rec_tagged (round-8 early-publish) unchanged.
// ---------------------------------------------------------------------------

#define BATCH 32
#define TSTEPS 150
#define C1N 1470            // 30*7*7 (trimmed: pooled conv2 only needs 7x7)
#define ZSEQN 70
#define HID1 512
#define HID2 1024
#define K1CAT 582           // rows: [rec(512) | conv(70)]
#define K2CAT 1094          // rows: [rec(1024) | conv(70)]

#define N_Z    (BATCH*TSTEPS*ZSEQN)   // 336,000
#define N_W1T  (K1CAT*HID1)           // 297,984
#define N_W2T  (K2CAT*HID2)           // 1,120,256
#define N_ST0  (BATCH*2*C1N)          // 94,080
#define N_ST2  (BATCH*2*ZSEQN)        // 4,480

// mask archive (u64): role1 [b][tt][32 words], role0 [b][tt][16 words]
#define A1_U64 (BATCH*TSTEPS*32)      // 153,600
#define A0_U64 (BATCH*TSTEPS*16)      // 76,800
#define N_ARCH_F ((A1_U64+A0_U64)*2)  // float-equivalents = 460,800 (1.84 MB)

// -------------------------------------------------------------------- K0 ---
__global__ void prep_weights(const float* __restrict__ l1_in_w,
                             const float* __restrict__ l1_rec_w,
                             const float* __restrict__ cl_in_w,
                             const float* __restrict__ cl_rec_w,
                             float* __restrict__ w1t,
                             float* __restrict__ w2t) {
    int idx = blockIdx.x * blockDim.x + threadIdx.x;
    int stride = gridDim.x * blockDim.x;
    for (int e = idx; e < N_W1T; e += stride) {
        int j = e / HID1, o = e - j * HID1;
        w1t[e] = (j < HID1) ? l1_rec_w[o * HID1 + j] : l1_in_w[o * 70 + (j - HID1)];
    }
    for (int e = idx; e < N_W2T; e += stride) {
        int j = e / HID2, o = e - j * HID2;
        w2t[e] = (j < HID2) ? cl_rec_w[o * HID2 + j] : cl_in_w[o * 70 + (j - HID2)];
    }
}

__global__ void init_arch(unsigned long long* __restrict__ arch) {
    size_t idx = (size_t)blockIdx.x * blockDim.x + threadIdx.x;
    size_t stride = (size_t)gridDim.x * blockDim.x;
    for (size_t e = idx; e < (A1_U64 + A0_U64); e += stride) arch[e] = 0ull;
}

// -------------------------------------------------------------------- K1 ---
__global__ __launch_bounds__(640) void conv1_pool(const float* __restrict__ x,
                                                  const float* __restrict__ w1,
                                                  const float* __restrict__ b1,
                                                  float* __restrict__ c1buf,
                                                  int t0, int CH) {
    __shared__ float img[2 * 34 * 34];
    __shared__ float w1s[30 * 2 * 49];
    __shared__ float crow[630 * 21];
    int bid = blockIdx.x;
    int b = bid / CH, tc = bid - b * CH;
    int t = t0 + tc;
    int tid = threadIdx.x;
    const float* xin = x + (size_t)(b * TSTEPS + t) * 2312;
    for (int e = tid; e < 2312; e += 640) img[e] = xin[e];
    for (int e = tid; e < 2940; e += 640) w1s[e] = w1[e];
    __syncthreads();
    if (tid < 630) {
        int oc = tid / 21, cy = tid - oc * 21;
        float acc[21];
        #pragma unroll
        for (int j = 0; j < 21; ++j) acc[j] = 0.f;
        #pragma unroll
        for (int ic = 0; ic < 2; ++ic) {
            const float* irow0 = &img[ic * 1156];
            const float* wrow = &w1s[(oc * 2 + ic) * 49];
            #pragma unroll
            for (int ky = 0; ky < 7; ++ky) {
                const float* ir = &irow0[(cy + ky) * 34];
                float r[27];
                #pragma unroll
                for (int j = 0; j < 27; ++j) r[j] = ir[j];
                #pragma unroll
                for (int kx = 0; kx < 7; ++kx) {
                    float w = wrow[ky * 7 + kx];
                    #pragma unroll
                    for (int cx = 0; cx < 21; ++cx)
                        acc[cx] = fmaf(r[cx + kx], w, acc[cx]);
                }
            }
        }
        #pragma unroll
        for (int cx = 0; cx < 21; ++cx) crow[tid * 21 + cx] = acc[cx];
    }
    __syncthreads();
    float* c1 = c1buf + (size_t)bid * C1N;
    for (int p = tid; p < C1N; p += 640) {
        int oc = p / 49; int r = p - oc * 49; int py = r / 7, px = r - py * 7;
        float m = -1e30f;
        #pragma unroll
        for (int dy = 0; dy < 3; ++dy) {
            int rowid = oc * 21 + 3 * py + dy;
            #pragma unroll
            for (int dx = 0; dx < 3; ++dx)
                m = fmaxf(m, crow[rowid * 21 + 3 * px + dx]);
        }
        c1[p] = m + b1[oc];
    }
}

// -------------------------------------------------------------------- K2 ---
// 8 WGs/batch, bid = w*32 + b  ->  bid%8 == b%8 (all stripes of a batch on
// one XCD; c1 stream HBM-fetched once per XCD). lif0 state in registers,
// double-buffered c1 LDS tile + one-step-ahead register prefetch,
// 3 barriers per step.
__global__ __launch_bounds__(320) void conv2_chain(const float* __restrict__ w2,
                                                   const float* __restrict__ b2,
                                                   const float* __restrict__ c1buf,
                                                   float* __restrict__ zbuf,
                                                   const float* __restrict__ st0_in,
                                                   float* __restrict__ st0_out,
                                                   const float* __restrict__ st2_in,
                                                   float* __restrict__ st2_out,
                                                   int t0, int CH) {
    int bid = blockIdx.x;
    int w = bid >> 5, b = bid & 31;
    int ocStart = w * 9;
    int nOc = (w == 7) ? 7 : 9;
    int tid = threadIdx.x;
    __shared__ float z0[C1N];            // 5.9 KB
    __shared__ float c1s[2][C1N];        // 11.8 KB
    __shared__ float w2s[9 * 750];       // 27 KB
    __shared__ float part[9 * 30 * 9];   // 9.7 KB
    __shared__ float red[81];
    for (int e = tid; e < nOc * 750; e += 320) w2s[e] = w2[ocStart * 750 + e];
    // lif0 state in registers: element e = tid + k*320
    float v0r[5], i0r[5];
    float v2 = 0.f, i2 = 0.f;
    if (t0 == 0) {
        #pragma unroll
        for (int k = 0; k < 5; ++k) { v0r[k] = 0.f; i0r[k] = 0.f; }
    } else {
        const float* s0 = st0_in + (size_t)b * 2 * C1N;
        #pragma unroll
        for (int k = 0; k < 5; ++k) {
            int e = tid + k * 320;
            v0r[k] = (e < C1N) ? s0[e] : 0.f;
            i0r[k] = (e < C1N) ? s0[C1N + e] : 0.f;
        }
        if (tid < nOc) {
            v2 = st2_in[b * ZSEQN + ocStart + tid];
            i2 = st2_in[BATCH * ZSEQN + b * ZSEQN + ocStart + tid];
        }
    }
    float bias2 = (tid < nOc) ? b2[ocStart + tid] : 0.f;
    const float* c1b = c1buf + (size_t)b * CH * C1N;
    float* zs = zbuf + (size_t)b * TSTEPS * ZSEQN;
    for (int e = tid; e < C1N; e += 320) c1s[0][e] = c1b[e];
    __syncthreads();
    int nConv = nOc * 30;
    for (int tc = 0; tc < CH; ++tc) {
        int cur = tc & 1, nxt = cur ^ 1;
        // ---- A: issue prefetch for tc+1; lif0 update (regs) -> z0 ----
        float pf[5];
        bool havePf = (tc + 1 < CH);
        if (havePf) {
            const float* c1n = c1b + (size_t)(tc + 1) * C1N;
            #pragma unroll
            for (int k = 0; k < 5; ++k) {
                int e = tid + k * 320;
                pf[k] = (e < C1N) ? c1n[e] : 0.f;
            }
        }
        #pragma unroll
        for (int k = 0; k < 5; ++k) {
            int e = tid + k * 320;
            if (e < C1N) {
                float vd = v0r[k] + 0.1f * (i0r[k] - v0r[k]);
                bool sp = (vd > 1.0f);
                v0r[k] = sp ? 0.f : vd;
                i0r[k] = i0r[k] - 0.2f * i0r[k] + c1s[cur][e];
                z0[e] = sp ? 1.f : 0.f;
            }
        }
        __syncthreads();                                   // B1: z0 ready
        // ---- B: conv partials; stash prefetch into c1s[nxt] ----
        if (tid < nConv) {
            int ol = tid / 30, ic = tid - ol * 30;
            float zw[49];
            #pragma unroll
            for (int j = 0; j < 49; ++j) zw[j] = z0[ic * 49 + j];
            float a[9];
            #pragma unroll
            for (int p = 0; p < 9; ++p) a[p] = 0.f;
            const float* wb = &w2s[ol * 750 + ic * 25];
            #pragma unroll
            for (int ky = 0; ky < 5; ++ky)
                #pragma unroll
                for (int kx = 0; kx < 5; ++kx) {
                    float wv = wb[ky * 5 + kx];
                    #pragma unroll
                    for (int cy = 0; cy < 3; ++cy)
                        #pragma unroll
                        for (int cx = 0; cx < 3; ++cx)
                            a[cy * 3 + cx] = fmaf(zw[(cy + ky) * 7 + cx + kx], wv, a[cy * 3 + cx]);
                }
            #pragma unroll
            for (int p = 0; p < 9; ++p) part[tid * 9 + p] = a[p];
        }
        if (havePf) {
            #pragma unroll
            for (int k = 0; k < 5; ++k) {
                int e = tid + k * 320;
                if (e < C1N) c1s[nxt][e] = pf[k];
            }
        }
        __syncthreads();                                   // B2: part + c1s[nxt]
        // ---- C: cross-ic reduction ----
        if (tid < nOc * 9) {
            int ol = tid / 9, pos = tid - ol * 9;
            float s = 0.f;
            for (int ic = 0; ic < 30; ++ic) s += part[(ol * 30 + ic) * 9 + pos];
            red[tid] = s;
        }
        __syncthreads();                                   // B3: red ready
        // ---- D: maxpool + lif2 + z store (overlaps next step's A) ----
        if (tid < nOc) {
            float m = -1e30f;
            #pragma unroll
            for (int p = 0; p < 9; ++p) m = fmaxf(m, red[tid * 9 + p]);
            float inp = m + bias2;
            float vd = v2 + 0.1f * (i2 - v2);
            float id = i2 - 0.2f * i2;
            bool sp = (vd > 1.0f);
            v2 = sp ? 0.f : vd;
            i2 = id + inp;
            zs[(size_t)(t0 + tc) * ZSEQN + ocStart + tid] = sp ? 1.f : 0.f;
        }
        // no end barrier: B1 of the next step orders z0/c1s reuse; red/part
        // reuse is >= 2 barriers away from their readers.
    }
    if (w == 0) {
        float* s0 = st0_out + (size_t)b * 2 * C1N;
        #pragma unroll
        for (int k = 0; k < 5; ++k) {
            int e = tid + k * 320;
            if (e < C1N) { s0[e] = v0r[k]; s0[C1N + e] = i0r[k]; }
        }
    }
    if (tid < nOc) {
        st2_out[b * ZSEQN + ocStart + tid] = v2;
        st2_out[BATCH * ZSEQN + b * ZSEQN + ocStart + tid] = i2;
    }
}

// -------------------------------------------------------------------- K3 ---
__device__ __forceinline__ float4 f4add(float4 a, const float4 b) {
    a.x += b.x; a.y += b.y; a.z += b.z; a.w += b.w; return a;
}
__device__ __forceinline__ void ast64(unsigned long long* p, unsigned long long v) {
    __hip_atomic_store(p, v, __ATOMIC_RELAXED, __HIP_MEMORY_SCOPE_AGENT);
}
__device__ __forceinline__ unsigned long long ald64(const unsigned long long* p) {
    return __hip_atomic_load((unsigned long long*)p, __ATOMIC_RELAXED,
                             __HIP_MEMORY_SCOPE_AGENT);
}

// One 64-col stripe of one chain per WG (256 threads).
// Per iteration tt: publish z(tt) FIRST (depends only on prior state),
// then gather cur(tt) (overlapping publish visibility), then poll peers.
template <int ROLE>
__device__ __forceinline__ void stripe_body(int b, int s,
        const float* __restrict__ zbuf,
        const float* __restrict__ catT,
        unsigned long long* __restrict__ arch) {   // this chain's archive
    constexpr int N   = ROLE ? HID2 : HID1;
    constexpr int K   = ROLE ? K2CAT : K1CAT;
    constexpr int SW  = N / 32;      // tagged words per step (== NW)
    constexpr int NW  = N / 32;
    constexpr int NWT = NW + 3;
    constexpr int N4  = N / 4;

    __shared__ float part[16 * 68];
    __shared__ unsigned short list[K2CAT];
    __shared__ unsigned int maskw[40];
    __shared__ unsigned int wprefix[40];

    const int t = threadIdx.x;
    const int lane = t & 63, wv = t >> 6;
    const int aid = t >> 4, qid = t & 15;    // 16 A-slices x 16 quads
    const int q0 = s * 16;

    const float* zsb = zbuf + (size_t)b * TSTEPS * ZSEQN;
    const float4* __restrict__ catT4 = (const float4*)catT;

    float v = 0.f, iacc = 0.f;

    // ---- initial list (step 0): rec bits zero, conv bits from zsb[0] ----
    if (t < NW) maskw[t] = 0u;
    {
        float zc = (t < 70) ? zsb[t] : 0.f;
        unsigned long long mc = __ballot(zc != 0.f);
        if (wv == 0 && lane == 0) { maskw[NW] = (unsigned)mc; maskw[NW + 1] = (unsigned)(mc >> 32); }
        if (wv == 1 && lane == 0) { maskw[NW + 2] = (unsigned)(mc & 0x3full); }
    }
    __syncthreads();
    if (wv == 0) {
        unsigned val = (lane < NWT) ? __popc(maskw[lane]) : 0u;
        #pragma unroll
        for (int d = 1; d < 64; d <<= 1) {
            unsigned u = __shfl_up(val, d);
            if (lane >= d) val += u;
        }
        if (lane < NWT) wprefix[lane + 1] = val;
        if (lane == 0) wprefix[0] = 0u;
    }
    __syncthreads();
    int A = wprefix[NWT];
    for (int jj = t; jj < K; jj += 256) {
        unsigned m = maskw[jj >> 5];
        if ((m >> (jj & 31)) & 1u)
            list[wprefix[jj >> 5] + __popc(m & ((1u << (jj & 31)) - 1u))] = (unsigned short)jj;
    }
    __syncthreads();

    // conv spikes for step 1's list (used at top of iteration 0)
    float znext = (t < 70 && 1 < TSTEPS) ? zsb[(size_t)1 * ZSEQN + t] : 0.f;

    for (int tt = 0; tt < TSTEPS; ++tt) {
        // ---- TOP: spike decision + publish (state from step tt-1 only) ----
        float vd = v + 0.1f * (iacc - v);
        bool sp = (t < 64) && (vd > 0.4f);
        float znew = sp ? 1.f : 0.f;
        if (t < 64) v = sp ? 0.f : vd;
        unsigned long long mz = __ballot(znew != 0.f);     // wave0 = all 64 cols
        if (wv == 0 && lane == 0) {
            unsigned long long tag = ((unsigned long long)(tt + 1)) << 32;
            ast64(arch + (size_t)tt * SW + s * 2,     tag | (unsigned)(mz & 0xffffffffull));
            ast64(arch + (size_t)tt * SW + s * 2 + 1, tag | (unsigned)(mz >> 32));
        }
        {   // conv bits zc(tt+1) for the next list (znext preloaded)
            unsigned long long mc = __ballot(znext != 0.f);
            if (wv == 0 && lane == 0) { maskw[NW] = (unsigned)mc; maskw[NW + 1] = (unsigned)(mc >> 32); }
            if (wv == 1 && lane == 0) { maskw[NW + 2] = (unsigned)(mc & 0x3full); }
        }
        // prefetch conv spikes for the following iteration
        znext = (t < 70 && tt + 2 < TSTEPS) ? zsb[(size_t)(tt + 2) * ZSEQN + t] : 0.f;
        // ---- gather active rows (list built from z(tt-1) + zc(tt)) ----
        float4 s0 = {0.f, 0.f, 0.f, 0.f}, s1 = s0, s2 = s0, s3 = s0;
        int idx = aid;
        for (; idx + 48 < A; idx += 64) {
            s0 = f4add(s0, catT4[(size_t)list[idx]      * N4 + q0 + qid]);
            s1 = f4add(s1, catT4[(size_t)list[idx + 16] * N4 + q0 + qid]);
            s2 = f4add(s2, catT4[(size_t)list[idx + 32] * N4 + q0 + qid]);
            s3 = f4add(s3, catT4[(size_t)list[idx + 48] * N4 + q0 + qid]);
        }
        for (; idx < A; idx += 16) s0 = f4add(s0, catT4[(size_t)list[idx] * N4 + q0 + qid]);
        s0 = f4add(f4add(s0, s1), f4add(s2, s3));
        *(float4*)(part + aid * 68 + 4 * qid) = s0;
        __syncthreads();                                   // B1: part + top LDS writes
        if (t < 64) {
            float cur = 0.f;
            #pragma unroll
            for (int a = 0; a < 16; ++a) cur += part[a * 68 + t];
            iacc = iacc - 0.2f * iacc + cur;
        }
        if (tt + 1 >= TSTEPS) break;                       // last step: no next list
        // ---- wave0: poll peers' z(tt) masks (in flight since TOP) ----
        if (wv == 0) {
            bool need = lane < SW;
            unsigned long long w = 0;
            for (;;) {
                if (need) w = ald64(arch + (size_t)tt * SW + lane);
                bool ok = !need || (unsigned)(w >> 32) == (unsigned)(tt + 1);
                if (__ballot(ok) == ~0ull) break;
                __builtin_amdgcn_s_sleep(1);
            }
            if (need) maskw[lane] = (unsigned)w;
            unsigned val = need ? __popc((unsigned)w)
                                : ((lane < NWT) ? __popc(maskw[lane]) : 0u);
            #pragma unroll
            for (int d = 1; d < 64; d <<= 1) {
                unsigned u = __shfl_up(val, d);
                if (lane >= d) val += u;
            }
            if (lane < NWT) wprefix[lane + 1] = val;
            if (lane == 0) wprefix[0] = 0u;
        }
        __syncthreads();                                   // B2: maskw/wprefix
        A = wprefix[NWT];
        for (int jj = t; jj < K; jj += 256) {
            unsigned m = maskw[jj >> 5];
            if ((m >> (jj & 31)) & 1u)
                list[wprefix[jj >> 5] + __popc(m & ((1u << (jj & 31)) - 1u))] = (unsigned short)jj;
        }
        __syncthreads();                                   // B3: list ready
    }
}

// Reader WG: trails the archive, computes fc readout + LI chain + final out.
template <int ROLE>
__device__ __forceinline__ void readout_body(int b,
        const float* __restrict__ fcw,
        const unsigned long long* __restrict__ arch,
        float* __restrict__ out) {
    constexpr int N  = ROLE ? HID2 : HID1;
    constexpr int SW = N / 32;
    constexpr int R  = ROLE ? 10 : 4;

    __shared__ unsigned int zw[32];
    __shared__ float wpart[40];
    __shared__ float mvals[10];

    const int t = threadIdx.x;
    const int lane = t & 63, wv = t >> 6;
    float vli = 0.f, ili = 0.f, rmax = -1e30f;

    for (int tt = 0; tt < TSTEPS; ++tt) {
        if (wv == 0) {
            bool need = lane < SW;
            unsigned long long w = 0;
            for (;;) {
                if (need) w = ald64(arch + (size_t)tt * SW + lane);
                bool ok = !need || (unsigned)(w >> 32) == (unsigned)(tt + 1);
                if (__ballot(ok) == ~0ull) break;
                __builtin_amdgcn_s_sleep(1);
            }
            if (need) zw[lane] = (unsigned)w;
        }
        __syncthreads();                                   // zw ready
        #pragma unroll
        for (int k = 0; k < R; ++k) {
            float p;
            if (ROLE) {
                unsigned bits = (zw[(t * 4) >> 5] >> ((t * 4) & 31)) & 0xFu;
                float4 w4 = ((const float4*)fcw)[k * (N / 4) + t];
                p = (bits & 1u ? w4.x : 0.f) + (bits & 2u ? w4.y : 0.f)
                  + (bits & 4u ? w4.z : 0.f) + (bits & 8u ? w4.w : 0.f);
            } else {
                unsigned bits = (zw[(t * 2) >> 5] >> ((t * 2) & 31)) & 0x3u;
                float2 w2 = ((const float2*)fcw)[k * (N / 2) + t];
                p = (bits & 1u ? w2.x : 0.f) + (bits & 2u ? w2.y : 0.f);
            }
            #pragma unroll
            for (int off = 32; off; off >>= 1) p += __shfl_xor(p, off);
            if (lane == 0) wpart[k * 4 + wv] = p;
        }
        __syncthreads();                                   // wpart ready
        if (t < R) {
            float inp = wpart[t * 4] + wpart[t * 4 + 1] + wpart[t * 4 + 2] + wpart[t * 4 + 3];
            float vn = vli + 0.1f * (ili - vli);
            ili = ili - 0.2f * ili + inp;
            vli = vn;
            rmax = fmaxf(rmax, vn);
        }
    }
    if (ROLE) {
        if (t < 10) mvals[t] = rmax;
        __syncthreads();
        if (t < 10) {
            float M = -1e30f;
            #pragma unroll
            for (int k = 0; k < 10; ++k) M = fmaxf(M, mvals[k]);
            float ssum = 0.f;
            #pragma unroll
            for (int k = 0; k < 10; ++k) ssum += expf(mvals[k] - M);
            out[BATCH * 4 + b * 10 + t] = mvals[t] - M - logf(ssum);
        }
    } else if (t < 4) {
        out[b * 4 + t] = rmax;
    }
}

__global__ __launch_bounds__(256) void rec_tagged(const float* __restrict__ fc_out_w,
                                                  const float* __restrict__ cl_fc_w,
                                                  const float* __restrict__ zbuf,
                                                  const float* __restrict__ w1t,
                                                  const float* __restrict__ w2t,
                                                  unsigned long long* __restrict__ arch1,
                                                  unsigned long long* __restrict__ arch0,
                                                  float* __restrict__ out) {
    int bid = blockIdx.x;
    if (bid < 512) {                       // role-1 stripes: bid%8 == s%8
        int b = bid >> 4, s = bid & 15;
        stripe_body<1>(b, s, zbuf, w2t, arch1 + (size_t)b * TSTEPS * 32);
    } else if (bid < 768) {                // role-0 stripes: bid%8 == s
        int idx = bid - 512;
        int b = idx >> 3, s = idx & 7;
        stripe_body<0>(b, s, zbuf, w1t, arch0 + (size_t)b * TSTEPS * 16);
    } else if (bid < 800) {
        int b = bid - 768;
        readout_body<1>(b, cl_fc_w, arch1 + (size_t)b * TSTEPS * 32, out);
    } else {
        int b = bid - 800;
        readout_body<0>(b, fc_out_w, arch0 + (size_t)b * TSTEPS * 16, out);
    }
}

// ---------------------------------------------------------------------------
extern "C" void kernel_launch(void* const* d_in, const int* in_sizes, int n_in,
                              void* d_out, int out_size, void* d_ws, size_t ws_size,
                              hipStream_t stream) {
    const float* x        = (const float*)d_in[0];
    const float* w1       = (const float*)d_in[1];
    const float* b1       = (const float*)d_in[2];
    const float* w2       = (const float*)d_in[3];
    const float* b2       = (const float*)d_in[4];
    const float* l1_in_w  = (const float*)d_in[5];
    const float* l1_rec_w = (const float*)d_in[6];
    const float* fc_out_w = (const float*)d_in[7];
    const float* cl_in_w  = (const float*)d_in[8];
    const float* cl_rec_w = (const float*)d_in[9];
    const float* cl_fc_w  = (const float*)d_in[10];
    float* out = (float*)d_out;
    float* ws  = (float*)d_ws;

    size_t base = (size_t)N_Z + N_W1T + N_W2T + N_ARCH_F + 2 * (N_ST0 + N_ST2);
    size_t avail = ws_size / 4;
    static const int divs[] = {150, 75, 50, 30, 25, 15, 10, 6, 5, 3, 2, 1};
    int CH = 1;
    for (int i = 0; i < 12; ++i) {
        size_t need = base + (size_t)BATCH * divs[i] * C1N;
        if (need <= avail) { CH = divs[i]; break; }
    }
    float* zbuf = ws;
    float* w1t  = zbuf + N_Z;
    float* w2t  = w1t + N_W1T;
    unsigned long long* arch1 = (unsigned long long*)(w2t + N_W2T);
    unsigned long long* arch0 = arch1 + A1_U64;
    float* st0a = (float*)(arch0 + A0_U64);
    float* st0b = st0a + N_ST0;
    float* st2a = st0b + N_ST0;
    float* st2b = st2a + N_ST2;
    float* c1buf = st2b + N_ST2;

    prep_weights<<<dim3(512), dim3(256), 0, stream>>>(l1_in_w, l1_rec_w,
                                                      cl_in_w, cl_rec_w, w1t, w2t);
    init_arch<<<dim3(64), dim3(256), 0, stream>>>(arch1);
    int nChunks = TSTEPS / CH;
    for (int c = 0; c < nChunks; ++c) {
        int t0 = c * CH;
        int par = c & 1;
        const float* s0i = par ? st0b : st0a;
        float*       s0o = par ? st0a : st0b;
        const float* s2i = par ? st2b : st2a;
        float*       s2o = par ? st2a : st2b;
        conv1_pool<<<dim3(BATCH * CH), dim3(640), 0, stream>>>(x, w1, b1, c1buf, t0, CH);
        conv2_chain<<<dim3(256), dim3(320), 0, stream>>>(w2, b2, c1buf, zbuf,
                                                         s0i, s0o, s2i, s2o, t0, CH);
    }
    rec_tagged<<<dim3(832), dim3(256), 0, stream>>>(fc_out_w, cl_fc_w, zbuf,
                                                    w1t, w2t, arch1, arch0, out);
}